// Round 2
// baseline (102.955 us; speedup 1.0000x reference)
//
#include <hip/hip_runtime.h>

#define IN_FEATURES 4096
#define OUT_FEATURES 11008
#define KO 128            // k-tiles per partition (2048/16)
#define NW 32             // int32 words per trellis block
#define SEG 16            // split-k segments per partition
#define KO_PER_SEG (KO / SEG)   // 8
#define SEGK (KO_PER_SEG * 16)  // 128 k-values per segment

// One thread = one output row (tx) of a 16x16 tile, 4 batch rows.
// x is staged transposed in LDS (xT[k][b]) so one broadcast ds_read_b128
// yields x[k] for all 4 batches. lut (4KB) in LDS; random 9-bit gather.
// Trellis fetch software-pipelined one k-tile ahead.
__global__ __launch_bounds__(256) void tcq_kernel(
    const float* __restrict__ inp,       // [4][4096]
    const int* __restrict__ trellis1,    // [688*128][32]
    const int* __restrict__ trellis2,
    const float* __restrict__ tlut,      // [512][2]
    float* __restrict__ out)             // [4][11008], pre-zeroed
{
    __shared__ float lut[1024];          // 4 KB
    __shared__ float xT[SEGK * 4];       // 2 KB, [k_local][b]

    const int tid  = threadIdx.x;
    const int part = blockIdx.z;
    const int ko0  = blockIdx.y * KO_PER_SEG;
    const float* __restrict__ xbase = inp + part * 2048 + ko0 * 16;

    ((float4*)lut)[tid] = ((const float4*)tlut)[tid];   // 256*16B = 4KB
    if (tid < SEGK) {
        #pragma unroll
        for (int b = 0; b < 4; ++b)
            xT[tid * 4 + b] = xbase[b * IN_FEATURES + tid];  // coalesced in tid
    }
    __syncthreads();

    const int lane = tid & 63;
    const int wid  = tid >> 6;
    const int tx   = lane & 15;          // row within tile
    const int mt   = lane >> 4;          // m-tile within wave
    const int mo   = blockIdx.x * 16 + wid * 4 + mt;   // global m-tile
    const int m    = mo * 16 + tx;

    const int* __restrict__ tre =
        (part ? trellis2 : trellis1) + (mo * KO + ko0) * NW;

    float accE[4] = {0.f, 0.f, 0.f, 0.f};
    float accO[4] = {0.f, 0.f, 0.f, 0.f};

    // software-pipelined trellis fetch (12B/thread per k-tile)
    int2 wp  = *reinterpret_cast<const int2*>(tre + 2 * tx);
    int  wm1 = tx ? tre[2 * tx - 1] : 0;

    #pragma unroll
    for (int kk = 0; kk < KO_PER_SEG; ++kk) {
        int2 wp_n = wp; int wm1_n = 0;
        if (kk + 1 < KO_PER_SEG) {
            const int* nb = tre + (kk + 1) * NW;
            wp_n  = *reinterpret_cast<const int2*>(nb + 2 * tx);
            wm1_n = tx ? nb[2 * tx - 1] : 0;
        }
        const unsigned comb0 = (unsigned(wm1)  << 16) | (unsigned(wp.x) & 0xFFFFu);
        const unsigned comb1 = (unsigned(wp.x) << 16) | (unsigned(wp.y) & 0xFFFFu);

        #pragma unroll
        for (int j = 0; j < 8; ++j) {
            const unsigned comb  = (j < 4) ? comb0 : comb1;
            const int      shift = 12 - 4 * (j & 3);
            const unsigned idx   = (comb >> shift) & 0x1FFu;
            float2 w  = *reinterpret_cast<const float2*>(&lut[idx * 2]);  // ds_read_b64 gather
            float4 xa = *reinterpret_cast<const float4*>(&xT[(kk * 16 + 2 * j) * 4]);     // broadcast
            float4 xb = *reinterpret_cast<const float4*>(&xT[(kk * 16 + 2 * j + 1) * 4]); // broadcast
            accE[0] = fmaf(w.x, xa.x, accE[0]);
            accE[1] = fmaf(w.x, xa.y, accE[1]);
            accE[2] = fmaf(w.x, xa.z, accE[2]);
            accE[3] = fmaf(w.x, xa.w, accE[3]);
            accO[0] = fmaf(w.y, xb.x, accO[0]);
            accO[1] = fmaf(w.y, xb.y, accO[1]);
            accO[2] = fmaf(w.y, xb.z, accO[2]);
            accO[3] = fmaf(w.y, xb.w, accO[3]);
        }
        wp = wp_n; wm1 = wm1_n;
    }

    #pragma unroll
    for (int b = 0; b < 4; ++b)
        atomicAdd(&out[b * OUT_FEATURES + m], accE[b] + accO[b]);
}

extern "C" void kernel_launch(void* const* d_in, const int* in_sizes, int n_in,
                              void* d_out, int out_size, void* d_ws, size_t ws_size,
                              hipStream_t stream) {
    const float* inp  = (const float*)d_in[0];
    const int*   t1   = (const int*)d_in[1];
    const int*   t2   = (const int*)d_in[2];
    const float* tlut = (const float*)d_in[3];
    float* out = (float*)d_out;

    hipMemsetAsync(out, 0, (size_t)out_size * sizeof(float), stream);

    dim3 grid(43, SEG, 2);   // 43 groups of 16 m-tiles, 16 k-segments, 2 partitions
    dim3 block(256);
    hipLaunchKernelGGL(tcq_kernel, grid, block, 0, stream,
                       inp, t1, t2, tlut, out);
}

// Round 3
// 96.903 us; speedup vs baseline: 1.0625x; 1.0625x over previous
//
#include <hip/hip_runtime.h>

#define IN_FEATURES 4096
#define OUT_FEATURES 11008
#define KO 128            // k-tiles per partition (2048/16)
#define NW 32             // int32 words per trellis block
#define SEG 32            // split-k segments per partition
#define KO_PER_SEG (KO / SEG)   // 4
#define NPART (SEG * 2)         // 64 partial sums per output element

// One thread = one output row (tx) of a 16x16 tile, 4 batch rows.
// x enters via wave-uniform loads -> s_load_dwordx16 -> SGPRs; FMA is
// v_fmac_f32 v, s, v (1 SGPR operand per instr is legal). LDS holds only the
// 4KB lut; the only LDS traffic is the random 9-bit b64 gather.
// Partials go to d_ws with plain coalesced stores (no atomics); a second
// kernel reduces the 64 partials per output.
__global__ __launch_bounds__(256, 6) void tcq_decode_kernel(
    const float* __restrict__ inp,       // [4][4096]
    const int* __restrict__ trellis1,    // [688*128][32]
    const int* __restrict__ trellis2,
    const float* __restrict__ tlut,      // [512][2]
    float* __restrict__ ws)              // [NPART][4][11008]
{
    __shared__ float lut[1024];          // 4 KB
    ((float4*)lut)[threadIdx.x] = ((const float4*)tlut)[threadIdx.x];
    __syncthreads();

    const int tid  = threadIdx.x;
    const int lane = tid & 63;
    const int wid  = tid >> 6;
    const int tx   = lane & 15;          // row within 16x16 tile
    const int mt   = lane >> 4;          // m-tile within wave
    const int mo   = blockIdx.x * 16 + wid * 4 + mt;   // global m-tile
    const int m    = mo * 16 + tx;
    const int seg  = blockIdx.y;
    const int part = blockIdx.z;
    const int ko0  = seg * KO_PER_SEG;

    const int* __restrict__ tre =
        (part ? trellis2 : trellis1) + (mo * KO + ko0) * NW;
    const float* __restrict__ xk = inp + part * 2048 + ko0 * 16;  // uniform

    float accE[4] = {0.f, 0.f, 0.f, 0.f};
    float accO[4] = {0.f, 0.f, 0.f, 0.f};

    #pragma unroll 1   // keep SGPR live-set to one k-tile of x (64 floats)
    for (int kk = 0; kk < KO_PER_SEG; ++kk) {
        const int* blk = tre + kk * NW;
        int2 wp  = *reinterpret_cast<const int2*>(blk + 2 * tx);
        int  wm1 = tx ? blk[2 * tx - 1] : 0;   // state starts at 0 per block
        const unsigned comb0 = (unsigned(wm1)  << 16) | (unsigned(wp.x) & 0xFFFFu);
        const unsigned comb1 = (unsigned(wp.x) << 16) | (unsigned(wp.y) & 0xFFFFu);

        // Wave-uniform address, uniform control flow -> scalar loads (SGPRs).
        float sx[4][16];
        #pragma unroll
        for (int b = 0; b < 4; ++b) {
            #pragma unroll
            for (int q = 0; q < 16; ++q)
                sx[b][q] = xk[b * IN_FEATURES + kk * 16 + q];
        }

        #pragma unroll
        for (int j = 0; j < 8; ++j) {
            const unsigned comb  = (j < 4) ? comb0 : comb1;
            const int      shift = 12 - 4 * (j & 3);
            const unsigned idx   = (comb >> shift) & 0x1FFu;
            float2 w = *reinterpret_cast<const float2*>(&lut[idx * 2]);  // b64 gather
            #pragma unroll
            for (int b = 0; b < 4; ++b) {
                accE[b] = fmaf(w.x, sx[b][2 * j],     accE[b]);
                accO[b] = fmaf(w.y, sx[b][2 * j + 1], accO[b]);
            }
        }
    }

    float* wsp = ws + (size_t)(part * SEG + seg) * 4 * OUT_FEATURES;
    #pragma unroll
    for (int b = 0; b < 4; ++b)
        wsp[b * OUT_FEATURES + m] = accE[b] + accO[b];   // coalesced, no atomics
}

__global__ __launch_bounds__(256) void tcq_reduce_kernel(
    const float* __restrict__ ws,        // [NPART][4*11008]
    float* __restrict__ out)             // [4*11008]
{
    const int i = blockIdx.x * 256 + threadIdx.x;
    if (i < 4 * OUT_FEATURES) {
        float s = 0.f;
        #pragma unroll
        for (int p = 0; p < NPART; ++p)
            s += ws[(size_t)p * 4 * OUT_FEATURES + i];
        out[i] = s;
    }
}

extern "C" void kernel_launch(void* const* d_in, const int* in_sizes, int n_in,
                              void* d_out, int out_size, void* d_ws, size_t ws_size,
                              hipStream_t stream) {
    const float* inp  = (const float*)d_in[0];
    const int*   t1   = (const int*)d_in[1];
    const int*   t2   = (const int*)d_in[2];
    const float* tlut = (const float*)d_in[3];
    float* out = (float*)d_out;
    float* ws  = (float*)d_ws;   // needs NPART*4*11008*4 B = 11.3 MB

    dim3 grid1(43, SEG, 2);      // 43 groups of 16 m-tiles, 32 k-segs, 2 parts
    hipLaunchKernelGGL(tcq_decode_kernel, grid1, dim3(256), 0, stream,
                       inp, t1, t2, tlut, ws);

    dim3 grid2((4 * OUT_FEATURES + 255) / 256);   // 172 blocks
    hipLaunchKernelGGL(tcq_reduce_kernel, grid2, dim3(256), 0, stream,
                       ws, out);
}